// Round 1
// baseline (4519.775 us; speedup 1.0000x reference)
//
#include <hip/hip_runtime.h>
#include <math.h>

#define D_MODEL 2048
#define NHEAD   16
#define HDIM    128
#define HALF    64
#define TSEQ    2048
#define BATCH   2
#define QKV_ROW (3*D_MODEL)   // 6144

// ---------------------------------------------------------------------------
// GEMM (NT): C[M,N] = A[M,K] @ W[N,K]^T + bias[N]
// 64x64 tile, TK=16, 256 threads, 4x4 micro-tile per thread. fp32 baseline.
// ---------------------------------------------------------------------------
__global__ __launch_bounds__(256)
void gemm_nt_bias(const float* __restrict__ A, const float* __restrict__ W,
                  const float* __restrict__ bias, float* __restrict__ C,
                  int M, int N, int K)
{
    __shared__ float As[64][17];
    __shared__ float Ws[64][17];
    const int tid = threadIdx.x;
    const int tx = tid & 15;
    const int ty = tid >> 4;
    const int row0 = blockIdx.y * 64;
    const int col0 = blockIdx.x * 64;

    const int lr = tid >> 2;        // 0..63
    const int lk = (tid & 3) << 2;  // 0,4,8,12
    const float* Aptr = A + (size_t)(row0 + lr) * K + lk;
    const float* Wptr = W + (size_t)(col0 + lr) * K + lk;

    float acc[4][4] = {};
    for (int kt = 0; kt < K; kt += 16) {
        float4 av = *(const float4*)(Aptr + kt);
        float4 wv = *(const float4*)(Wptr + kt);
        As[lr][lk + 0] = av.x; As[lr][lk + 1] = av.y;
        As[lr][lk + 2] = av.z; As[lr][lk + 3] = av.w;
        Ws[lr][lk + 0] = wv.x; Ws[lr][lk + 1] = wv.y;
        Ws[lr][lk + 2] = wv.z; Ws[lr][lk + 3] = wv.w;
        __syncthreads();
        #pragma unroll
        for (int kk = 0; kk < 16; ++kk) {
            float a[4], b[4];
            #pragma unroll
            for (int i = 0; i < 4; ++i) a[i] = As[ty + 16*i][kk];
            #pragma unroll
            for (int j = 0; j < 4; ++j) b[j] = Ws[tx + 16*j][kk];
            #pragma unroll
            for (int i = 0; i < 4; ++i)
                #pragma unroll
                for (int j = 0; j < 4; ++j)
                    acc[i][j] += a[i] * b[j];
        }
        __syncthreads();
    }
    #pragma unroll
    for (int i = 0; i < 4; ++i) {
        const int r = row0 + ty + 16*i;
        #pragma unroll
        for (int j = 0; j < 4; ++j) {
            const int c = col0 + tx + 16*j;
            C[(size_t)r * N + c] = acc[i][j] + bias[c];
        }
    }
}

// ---------------------------------------------------------------------------
// RoPE in-place on q and k inside qkv buffer; folds softmax scale into q.
// One thread per (b,t,h,i), i in [0,64).
// ---------------------------------------------------------------------------
__global__ __launch_bounds__(256)
void rope_kernel(float* __restrict__ qkv)
{
    const int idx = blockIdx.x * 256 + threadIdx.x;
    const int i  = idx & (HALF - 1);
    const int h  = (idx >> 6) & (NHEAD - 1);
    const int bt = idx >> 10;            // 0..B*T-1
    const int t  = bt & (TSEQ - 1);

    // theta = 10000^(-i/64) = 2^(-i * log2(10000)/64)
    const float theta = exp2f(-(float)i * (13.287712379549449f / 64.0f));
    float s, c;
    sincosf((float)t * theta, &s, &c);

    const float scale = 0.022097086912079608f;  // 2048^-0.5, folded into q

    float* base = qkv + (size_t)bt * QKV_ROW + h * (3 * HDIM);
    // q
    {
        float t1 = base[i], t2 = base[i + HALF];
        base[i]        = (t1 * c - t2 * s) * scale;
        base[i + HALF] = (t1 * s + t2 * c) * scale;
    }
    // k
    {
        float t1 = base[HDIM + i], t2 = base[HDIM + i + HALF];
        base[HDIM + i]        = t1 * c - t2 * s;
        base[HDIM + i + HALF] = t1 * s + t2 * c;
    }
}

// ---------------------------------------------------------------------------
// Causal flash attention. One block per (b, h, 32-row q tile). 256 threads.
// Thread (r = tid>>3, lane8 = tid&7): 4 score cols (j*8+lane8),
// 16 O cols (cc*8+lane8). Online softmax state per row, replicated
// across the row's 8 lanes (kept consistent via shuffles).
// ---------------------------------------------------------------------------
__global__ __launch_bounds__(256)
void attn_kernel(const float* __restrict__ qkv, float* __restrict__ attn)
{
    __shared__ float Qs[32][132];
    __shared__ float Ks[32][132];
    __shared__ float Vs[32][132];
    __shared__ float Ps[32][33];

    const int tid   = threadIdx.x;
    const int lane8 = tid & 7;
    const int r     = tid >> 3;        // 0..31
    const int qb    = blockIdx.x;      // q tile
    const int h     = blockIdx.y;
    const int b     = blockIdx.z;
    const int q0    = qb * 32;

    const float* base = qkv + (size_t)b * TSEQ * QKV_ROW + h * (3 * HDIM);

    // Load Q tile (32 x 128)
    for (int x = tid; x < 32 * 32; x += 256) {
        const int rr = x >> 5, c4 = (x & 31) << 2;
        float4 v = *(const float4*)(base + (size_t)(q0 + rr) * QKV_ROW + c4);
        Qs[rr][c4 + 0] = v.x; Qs[rr][c4 + 1] = v.y;
        Qs[rr][c4 + 2] = v.z; Qs[rr][c4 + 3] = v.w;
    }

    float O[16];
    #pragma unroll
    for (int cc = 0; cc < 16; ++cc) O[cc] = 0.f;
    float m_prev = -1e30f, l = 0.f;

    const int qi = q0 + r;

    for (int kb = 0; kb <= qb; ++kb) {
        __syncthreads();   // previous iteration done with Ks/Vs/Ps (also fences Q load)
        for (int x = tid; x < 32 * 32; x += 256) {
            const int rr = x >> 5, c4 = (x & 31) << 2;
            const float* krow = base + (size_t)(kb * 32 + rr) * QKV_ROW;
            float4 kv = *(const float4*)(krow + HDIM + c4);
            Ks[rr][c4 + 0] = kv.x; Ks[rr][c4 + 1] = kv.y;
            Ks[rr][c4 + 2] = kv.z; Ks[rr][c4 + 3] = kv.w;
            float4 vv = *(const float4*)(krow + 2 * HDIM + c4);
            Vs[rr][c4 + 0] = vv.x; Vs[rr][c4 + 1] = vv.y;
            Vs[rr][c4 + 2] = vv.z; Vs[rr][c4 + 3] = vv.w;
        }
        __syncthreads();

        // S tile: each thread 4 columns c = j*8 + lane8
        float s[4] = {0.f, 0.f, 0.f, 0.f};
        #pragma unroll 8
        for (int d4 = 0; d4 < 32; ++d4) {
            const float4 qv = *(const float4*)&Qs[r][d4 << 2];
            #pragma unroll
            for (int j = 0; j < 4; ++j) {
                const float4 kv = *(const float4*)&Ks[(j << 3) + lane8][d4 << 2];
                s[j] += qv.x * kv.x + qv.y * kv.y + qv.z * kv.z + qv.w * kv.w;
            }
        }
        // causal mask (scale already folded into q)
        #pragma unroll
        for (int j = 0; j < 4; ++j) {
            const int ki = kb * 32 + (j << 3) + lane8;
            if (ki > qi) s[j] = -1e30f;
        }

        // row max across 4 locals + 8 lanes
        float mt = fmaxf(fmaxf(s[0], s[1]), fmaxf(s[2], s[3]));
        mt = fmaxf(mt, __shfl_xor(mt, 1));
        mt = fmaxf(mt, __shfl_xor(mt, 2));
        mt = fmaxf(mt, __shfl_xor(mt, 4));
        const float m_new = fmaxf(m_prev, mt);
        const float alpha = __expf(m_prev - m_new);

        float p[4], psum = 0.f;
        #pragma unroll
        for (int j = 0; j < 4; ++j) { p[j] = __expf(s[j] - m_new); psum += p[j]; }
        psum += __shfl_xor(psum, 1);
        psum += __shfl_xor(psum, 2);
        psum += __shfl_xor(psum, 4);
        l = l * alpha + psum;
        m_prev = m_new;

        #pragma unroll
        for (int cc = 0; cc < 16; ++cc) O[cc] *= alpha;
        #pragma unroll
        for (int j = 0; j < 4; ++j) Ps[r][(j << 3) + lane8] = p[j];
        __syncthreads();

        // O += P @ V  (thread's 16 cols: cc*8 + lane8 -- conflict-free)
        #pragma unroll 8
        for (int j = 0; j < 32; ++j) {
            const float pv = Ps[r][j];
            #pragma unroll
            for (int cc = 0; cc < 16; ++cc)
                O[cc] += pv * Vs[j][(cc << 3) + lane8];
        }
    }

    const float inv_l = 1.f / l;
    float* orow = attn + ((size_t)b * TSEQ + q0 + r) * D_MODEL + h * HDIM;
    #pragma unroll
    for (int cc = 0; cc < 16; ++cc)
        orow[(cc << 3) + lane8] = O[cc] * inv_l;
}

// ---------------------------------------------------------------------------
extern "C" void kernel_launch(void* const* d_in, const int* in_sizes, int n_in,
                              void* d_out, int out_size, void* d_ws, size_t ws_size,
                              hipStream_t stream)
{
    const float* x     = (const float*)d_in[0];  // (B,T,D)
    const float* w_qkv = (const float*)d_in[1];  // (3D, D)
    const float* b_qkv = (const float*)d_in[2];  // (3D,)
    const float* w_out = (const float*)d_in[3];  // (D, D)
    const float* b_out = (const float*)d_in[4];  // (D,)
    float* out = (float*)d_out;                  // (B,T,D)

    const int M = BATCH * TSEQ;                  // 4096
    float* qkv  = (float*)d_ws;                  // M x 6144
    float* attn = qkv + (size_t)M * QKV_ROW;     // M x 2048

    // 1) qkv = x @ w_qkv^T + b_qkv
    {
        dim3 g(QKV_ROW / 64, M / 64);
        gemm_nt_bias<<<g, 256, 0, stream>>>(x, w_qkv, b_qkv, qkv, M, QKV_ROW, D_MODEL);
    }
    // 2) RoPE on q,k (+ fold softmax scale into q)
    {
        const int total = BATCH * TSEQ * NHEAD * HALF;   // 4,194,304
        rope_kernel<<<total / 256, 256, 0, stream>>>(qkv);
    }
    // 3) causal flash attention -> attn (B,T,D) layout
    {
        dim3 g(TSEQ / 32, NHEAD, BATCH);
        attn_kernel<<<g, 256, 0, stream>>>(qkv, attn);
    }
    // 4) out = attn @ w_out^T + b_out
    {
        dim3 g(D_MODEL / 64, M / 64);
        gemm_nt_bias<<<g, 256, 0, stream>>>(attn, w_out, b_out, out, M, D_MODEL, D_MODEL);
    }
}

// Round 2
// 501.648 us; speedup vs baseline: 9.0099x; 9.0099x over previous
//
#include <hip/hip_runtime.h>
#include <math.h>

#define NHEAD 16
#define TSEQ  2048
#define BATCH 2
#define DM    2048
#define QROW  6144   // 3*DM

typedef __attribute__((ext_vector_type(8))) short bf16x8;
typedef __attribute__((ext_vector_type(4))) float f32x4;

__device__ __forceinline__ short f2bf(float f) {
    unsigned u = __builtin_bit_cast(unsigned, f);
    u += 0x7fff + ((u >> 16) & 1);          // RNE
    return (short)(u >> 16);
}
__device__ __forceinline__ float bf2f(short s) {
    unsigned u = ((unsigned)(unsigned short)s) << 16;
    return __builtin_bit_cast(float, u);
}
__device__ __forceinline__ void gload_lds16(const void* g, void* l) {
    __builtin_amdgcn_global_load_lds(
        (const __attribute__((address_space(1))) unsigned int*)g,
        (__attribute__((address_space(3))) unsigned int*)l, 16, 0, 0);
}

// ---------------------------------------------------------------------------
// fp32 -> bf16 cast, 8 elems/thread
// ---------------------------------------------------------------------------
__global__ __launch_bounds__(256)
void cast_f32_bf16(const float* __restrict__ in, short* __restrict__ out, int n)
{
    int i = (blockIdx.x * 256 + threadIdx.x) * 8;
    if (i >= n) return;
    float4 a = *(const float4*)(in + i);
    float4 b = *(const float4*)(in + i + 4);
    bf16x8 o;
    o[0]=f2bf(a.x); o[1]=f2bf(a.y); o[2]=f2bf(a.z); o[3]=f2bf(a.w);
    o[4]=f2bf(b.x); o[5]=f2bf(b.y); o[6]=f2bf(b.z); o[7]=f2bf(b.w);
    *(bf16x8*)(out + i) = o;
}

// ---------------------------------------------------------------------------
// bf16 MFMA GEMM (NT): C[M,N] = A[M,K] @ W[N,K]^T + bias.  m97 structure:
// 128x128 tile, BK=64, global_load_lds(16B), XOR-8 swizzled LDS chunks so
// ds_read_b128 fragment reads are 2-way (free) bank-aliased.
// 4 waves in 2x2, each 64x64 via 4x4 grid of 16x16x32 MFMAs.
// ---------------------------------------------------------------------------
template<bool BF16_OUT>
__global__ __launch_bounds__(256)
void gemm_bf16_nt(const short* __restrict__ A, const short* __restrict__ W,
                  const float* __restrict__ bias, void* __restrict__ Cout,
                  int N, int K)
{
    __shared__ short As[128 * 64];
    __shared__ short Bs[128 * 64];
    const int tid = threadIdx.x;
    const int lane = tid & 63, w = tid >> 6;
    const int lane15 = lane & 15, quad = lane >> 4;
    const int wr = w >> 1, wc = w & 1;
    const int row0 = blockIdx.y * 128, col0 = blockIdx.x * 128;

    f32x4 acc[4][4];
    #pragma unroll
    for (int mi = 0; mi < 4; ++mi)
        #pragma unroll
        for (int ni = 0; ni < 4; ++ni)
            acc[mi][ni] = (f32x4){0.f, 0.f, 0.f, 0.f};

    for (int kt = 0; kt < K; kt += 64) {
        __syncthreads();
        #pragma unroll
        for (int i = 0; i < 4; ++i) {
            int ci = i * 256 + tid;                  // 0..1023 chunk id
            int row = ci >> 3, lc = ci & 7;
            int gc = lc ^ (row & 7);                 // swizzle
            gload_lds16(A + (size_t)(row0 + row) * K + kt + gc * 8, As + ci * 8);
            gload_lds16(W + (size_t)(col0 + row) * K + kt + gc * 8, Bs + ci * 8);
        }
        __syncthreads();
        #pragma unroll
        for (int kc = 0; kc < 2; ++kc) {
            bf16x8 af[4], bfr[4];
            #pragma unroll
            for (int mi = 0; mi < 4; ++mi) {
                int r = wr * 64 + mi * 16 + lane15;
                af[mi] = *(const bf16x8*)(As + r * 64 + ((kc * 4 + quad) ^ (r & 7)) * 8);
            }
            #pragma unroll
            for (int ni = 0; ni < 4; ++ni) {
                int r = wc * 64 + ni * 16 + lane15;
                bfr[ni] = *(const bf16x8*)(Bs + r * 64 + ((kc * 4 + quad) ^ (r & 7)) * 8);
            }
            #pragma unroll
            for (int mi = 0; mi < 4; ++mi)
                #pragma unroll
                for (int ni = 0; ni < 4; ++ni)
                    acc[mi][ni] = __builtin_amdgcn_mfma_f32_16x16x32_bf16(
                        af[mi], bfr[ni], acc[mi][ni], 0, 0, 0);
        }
    }

    #pragma unroll
    for (int mi = 0; mi < 4; ++mi) {
        #pragma unroll
        for (int ni = 0; ni < 4; ++ni) {
            int col = col0 + wc * 64 + ni * 16 + lane15;
            float bv = bias[col];
            #pragma unroll
            for (int r = 0; r < 4; ++r) {
                int row = row0 + wr * 64 + mi * 16 + quad * 4 + r;
                float v = acc[mi][ni][r] + bv;
                if (BF16_OUT) ((short*)Cout)[(size_t)row * N + col] = f2bf(v);
                else          ((float*)Cout)[(size_t)row * N + col] = v;
            }
        }
    }
}

// ---------------------------------------------------------------------------
// RoPE (in place, bf16, fp32 math, softmax scale folded into q) + build
// V^T buffer vtb[b][h][dim][t] for DMA-friendly PV staging.
// Block per (t-tile of 64, h, b).
// ---------------------------------------------------------------------------
__global__ __launch_bounds__(256)
void rope_vt(short* __restrict__ qkvb, short* __restrict__ vtb)
{
    __shared__ short Vsm[64][136];
    const int tid = threadIdx.x;
    const int tt0 = blockIdx.x * 64;
    const int h = blockIdx.y, b = blockIdx.z;
    short* base = qkvb + (size_t)b * TSEQ * QROW + h * 384;

    // stage V tile [64 t][128 d]
    for (int x = tid; x < 1024; x += 256) {
        int row = x >> 4, c8 = (x & 15) << 3;
        *(bf16x8*)&Vsm[row][c8] =
            *(const bf16x8*)(base + (size_t)(tt0 + row) * QROW + 256 + c8);
    }
    // rope q,k
    for (int x = tid; x < 4096; x += 256) {
        int row = x >> 6, i = x & 63;
        int t = tt0 + row;
        float theta = exp2f(-(float)i * (13.287712379549449f / 64.0f));
        float s, c;
        sincosf((float)t * theta, &s, &c);
        short* p = base + (size_t)t * QROW;
        float q1 = bf2f(p[i]), q2 = bf2f(p[i + 64]);
        float k1 = bf2f(p[128 + i]), k2 = bf2f(p[128 + i + 64]);
        const float sc = 0.022097086912079608f;   // 2048^-0.5 folded into q
        p[i]            = f2bf((q1 * c - q2 * s) * sc);
        p[i + 64]       = f2bf((q1 * s + q2 * c) * sc);
        p[128 + i]      = f2bf(k1 * c - k2 * s);
        p[128 + i + 64] = f2bf(k1 * s + k2 * c);
    }
    __syncthreads();
    // write transposed V
    for (int x = tid; x < 1024; x += 256) {
        int d = x >> 3, t8 = (x & 7) << 3;
        bf16x8 v;
        #pragma unroll
        for (int j = 0; j < 8; ++j) v[j] = Vsm[t8 + j][d];
        *(bf16x8*)(vtb + (((size_t)b * NHEAD + h) * 128 + d) * TSEQ + tt0 + t8) = v;
    }
}

// ---------------------------------------------------------------------------
// MFMA flash attention. Block per (64-row q tile, h, b); 4 waves, wave w owns
// q rows [q0+16w, +16). K/V tiles of 64 keys staged by global_load_lds with
// XOR swizzle. S and O in MFMA C-layout; P round-trips LDS (stride 68 fp32)
// into A-layout for PV.
// ---------------------------------------------------------------------------
__global__ __launch_bounds__(256)
void attn_mfma(const short* __restrict__ qkvb, const short* __restrict__ vtb,
               short* __restrict__ attnb)
{
    __shared__ short Ks[64 * 128];    // [key][dim]
    __shared__ short Vs[128 * 64];    // [dim][key]  (from vtb)
    __shared__ float Ps[4 * 16 * 68]; // per-wave 16x64, stride 68

    const int tid = threadIdx.x;
    const int lane = tid & 63, w = tid >> 6;
    const int lane15 = lane & 15, quad = lane >> 4;
    const int qb = blockIdx.x, h = blockIdx.y, b = blockIdx.z;
    const int q0 = qb * 64;

    const short* base  = qkvb + (size_t)b * TSEQ * QROW + h * 384;
    const short* vbase = vtb + ((size_t)b * NHEAD + h) * 128 * TSEQ;
    float* Pw = Ps + w * (16 * 68);

    // Q fragments (A-layout): row = lane15 within wave's 16 rows
    bf16x8 qf[4];
    {
        const short* qrow = base + (size_t)(q0 + w * 16 + lane15) * QROW;
        #pragma unroll
        for (int kc = 0; kc < 4; ++kc)
            qf[kc] = *(const bf16x8*)(qrow + kc * 32 + quad * 8);
    }

    f32x4 O[8];
    #pragma unroll
    for (int i = 0; i < 8; ++i) O[i] = (f32x4){0.f, 0.f, 0.f, 0.f};
    float m_r[4], l_r[4];
    #pragma unroll
    for (int r = 0; r < 4; ++r) { m_r[r] = -1e30f; l_r[r] = 0.f; }

    for (int kb = 0; kb <= qb; ++kb) {
        __syncthreads();
        #pragma unroll
        for (int i = 0; i < 4; ++i) {
            int ci = i * 256 + tid;
            {   // K tile [64][128]
                int row = ci >> 4, lc = ci & 15;
                int gc = (lc & 8) | ((lc ^ row) & 7);
                gload_lds16(base + (size_t)(kb * 64 + row) * QROW + 128 + gc * 8,
                            Ks + ci * 8);
            }
            {   // Vt tile [128][64]
                int row = ci >> 3, lc = ci & 7;
                int gc = lc ^ (row & 7);
                gload_lds16(vbase + (size_t)row * TSEQ + kb * 64 + gc * 8,
                            Vs + ci * 8);
            }
        }
        __syncthreads();

        // S = Q K^T : wave's 16 rows x 64 keys
        f32x4 s[4];
        #pragma unroll
        for (int ni = 0; ni < 4; ++ni) s[ni] = (f32x4){0.f, 0.f, 0.f, 0.f};
        #pragma unroll
        for (int ni = 0; ni < 4; ++ni) {
            int krow = ni * 16 + lane15;
            #pragma unroll
            for (int kc = 0; kc < 4; ++kc) {
                int lc = kc * 4 + quad;
                int pc = (lc & 8) | ((lc ^ krow) & 7);
                bf16x8 kf = *(const bf16x8*)(Ks + krow * 128 + pc * 8);
                s[ni] = __builtin_amdgcn_mfma_f32_16x16x32_bf16(qf[kc], kf, s[ni], 0, 0, 0);
            }
        }

        if (kb == qb) {   // diagonal tile: causal mask
            const int qi = q0 + w * 16 + quad * 4;
            #pragma unroll
            for (int ni = 0; ni < 4; ++ni) {
                int key = kb * 64 + ni * 16 + lane15;
                #pragma unroll
                for (int r = 0; r < 4; ++r)
                    if (key > qi + r) s[ni][r] = -1e30f;
            }
        }

        // online softmax (rows live on reg r within 16-lane groups)
        float mt[4];
        #pragma unroll
        for (int r = 0; r < 4; ++r)
            mt[r] = fmaxf(fmaxf(s[0][r], s[1][r]), fmaxf(s[2][r], s[3][r]));
        #pragma unroll
        for (int off = 1; off <= 8; off <<= 1)
            #pragma unroll
            for (int r = 0; r < 4; ++r)
                mt[r] = fmaxf(mt[r], __shfl_xor(mt[r], off));
        float alpha[4];
        #pragma unroll
        for (int r = 0; r < 4; ++r) {
            float mn = fmaxf(m_r[r], mt[r]);
            alpha[r] = __expf(m_r[r] - mn);
            m_r[r] = mn;
        }
        float ps[4] = {0.f, 0.f, 0.f, 0.f};
        #pragma unroll
        for (int ni = 0; ni < 4; ++ni)
            #pragma unroll
            for (int r = 0; r < 4; ++r) {
                float p = __expf(s[ni][r] - m_r[r]);
                s[ni][r] = p;
                ps[r] += p;
            }
        #pragma unroll
        for (int off = 1; off <= 8; off <<= 1)
            #pragma unroll
            for (int r = 0; r < 4; ++r)
                ps[r] += __shfl_xor(ps[r], off);
        #pragma unroll
        for (int r = 0; r < 4; ++r) l_r[r] = l_r[r] * alpha[r] + ps[r];
        #pragma unroll
        for (int i = 0; i < 8; ++i)
            #pragma unroll
            for (int r = 0; r < 4; ++r) O[i][r] *= alpha[r];

        // P (C-layout) -> LDS; stride 68 keeps both sides 2-way-aliased
        #pragma unroll
        for (int ni = 0; ni < 4; ++ni)
            #pragma unroll
            for (int r = 0; r < 4; ++r)
                Pw[(quad * 4 + r) * 68 + ni * 16 + lane15] = s[ni][r];

        // O += P @ V  (P re-read in A-layout; same wave, no barrier needed)
        #pragma unroll
        for (int kc = 0; kc < 2; ++kc) {
            const float* pr = Pw + lane15 * 68 + kc * 32 + quad * 8;
            bf16x8 pf;
            #pragma unroll
            for (int j = 0; j < 8; ++j) pf[j] = f2bf(pr[j]);
            #pragma unroll
            for (int ni = 0; ni < 8; ++ni) {
                int vrow = ni * 16 + lane15;
                int pc = (kc * 4 + quad) ^ (vrow & 7);
                bf16x8 vf = *(const bf16x8*)(Vs + vrow * 64 + pc * 8);
                O[ni] = __builtin_amdgcn_mfma_f32_16x16x32_bf16(pf, vf, O[ni], 0, 0, 0);
            }
        }
    }

    // epilogue: O / l -> bf16 attnb[b,t,D]
    short* orow = attnb + ((size_t)b * TSEQ + q0 + w * 16) * DM + h * 128;
    #pragma unroll
    for (int ni = 0; ni < 8; ++ni)
        #pragma unroll
        for (int r = 0; r < 4; ++r)
            orow[(size_t)(quad * 4 + r) * DM + ni * 16 + lane15] =
                f2bf(O[ni][r] / l_r[r]);
}

// ---------------------------------------------------------------------------
extern "C" void kernel_launch(void* const* d_in, const int* in_sizes, int n_in,
                              void* d_out, int out_size, void* d_ws, size_t ws_size,
                              hipStream_t stream)
{
    const float* x     = (const float*)d_in[0];
    const float* w_qkv = (const float*)d_in[1];
    const float* b_qkv = (const float*)d_in[2];
    const float* w_out = (const float*)d_in[3];
    const float* b_out = (const float*)d_in[4];
    float* out = (float*)d_out;

    char* ws = (char*)d_ws;
    short* xb    = (short*)(ws);                 // 16.78 MB (reused as attnb)
    short* wqkvb = (short*)(ws + 16777216);      // 25.17 MB
    short* woutb = (short*)(ws + 41943040);      //  8.39 MB
    short* qkvb  = (short*)(ws + 50331648);      // 50.33 MB
    short* vtb   = (short*)(ws + 100663296);     // 16.78 MB   (total 117.4 MB)
    short* attnb = xb;                            // x dead after QKV GEMM

    cast_f32_bf16<<<4096, 256, 0, stream>>>(x, xb, 8388608);
    cast_f32_bf16<<<6144, 256, 0, stream>>>(w_qkv, wqkvb, 12582912);
    cast_f32_bf16<<<2048, 256, 0, stream>>>(w_out, woutb, 4194304);

    {   // qkv = x @ w_qkv^T + b_qkv  (bf16 out)
        dim3 g(6144 / 128, 4096 / 128);
        gemm_bf16_nt<true><<<g, 256, 0, stream>>>(xb, wqkvb, b_qkv, qkvb, 6144, 2048);
    }
    {   // rope q,k in place + V^T
        dim3 g(TSEQ / 64, NHEAD, BATCH);
        rope_vt<<<g, 256, 0, stream>>>(qkvb, vtb);
    }
    {   // flash attention
        dim3 g(TSEQ / 64, NHEAD, BATCH);
        attn_mfma<<<g, 256, 0, stream>>>(qkvb, vtb, attnb);
    }
    {   // out = attn @ w_out^T + b_out  (fp32 out)
        dim3 g(2048 / 128, 4096 / 128);
        gemm_bf16_nt<false><<<g, 256, 0, stream>>>(attnb, woutb, b_out, out, 2048, 2048);
    }
}

// Round 3
// 393.642 us; speedup vs baseline: 11.4820x; 1.2744x over previous
//
#include <hip/hip_runtime.h>
#include <math.h>

#define NHEAD 16
#define TSEQ  2048
#define BATCH 2
#define DM    2048
#define QROW  6144   // 3*DM

typedef __attribute__((ext_vector_type(8))) short bf16x8;
typedef __attribute__((ext_vector_type(4))) float f32x4;

__device__ __forceinline__ short f2bf(float f) {
    unsigned u = __builtin_bit_cast(unsigned, f);
    u += 0x7fff + ((u >> 16) & 1);          // RNE
    return (short)(u >> 16);
}
__device__ __forceinline__ float bf2f(short s) {
    unsigned u = ((unsigned)(unsigned short)s) << 16;
    return __builtin_bit_cast(float, u);
}
__device__ __forceinline__ void gload_lds16(const void* g, void* l) {
    __builtin_amdgcn_global_load_lds(
        (const __attribute__((address_space(1))) unsigned int*)g,
        (__attribute__((address_space(3))) unsigned int*)l, 16, 0, 0);
}

// ---------------------------------------------------------------------------
__global__ __launch_bounds__(256)
void cast_f32_bf16(const float* __restrict__ in, short* __restrict__ out, int n)
{
    int i = (blockIdx.x * 256 + threadIdx.x) * 8;
    if (i >= n) return;
    float4 a = *(const float4*)(in + i);
    float4 b = *(const float4*)(in + i + 4);
    bf16x8 o;
    o[0]=f2bf(a.x); o[1]=f2bf(a.y); o[2]=f2bf(a.z); o[3]=f2bf(a.w);
    o[4]=f2bf(b.x); o[5]=f2bf(b.y); o[6]=f2bf(b.z); o[7]=f2bf(b.w);
    *(bf16x8*)(out + i) = o;
}

// ---------------------------------------------------------------------------
// bf16 MFMA GEMM (NT), m97 structure (unchanged from round 2 — works).
// ---------------------------------------------------------------------------
template<bool BF16_OUT>
__global__ __launch_bounds__(256)
void gemm_bf16_nt(const short* __restrict__ A, const short* __restrict__ W,
                  const float* __restrict__ bias, void* __restrict__ Cout,
                  int N, int K)
{
    __shared__ short As[128 * 64];
    __shared__ short Bs[128 * 64];
    const int tid = threadIdx.x;
    const int lane = tid & 63, w = tid >> 6;
    const int lane15 = lane & 15, quad = lane >> 4;
    const int wr = w >> 1, wc = w & 1;
    const int row0 = blockIdx.y * 128, col0 = blockIdx.x * 128;

    f32x4 acc[4][4];
    #pragma unroll
    for (int mi = 0; mi < 4; ++mi)
        #pragma unroll
        for (int ni = 0; ni < 4; ++ni)
            acc[mi][ni] = (f32x4){0.f, 0.f, 0.f, 0.f};

    for (int kt = 0; kt < K; kt += 64) {
        __syncthreads();
        #pragma unroll
        for (int i = 0; i < 4; ++i) {
            int ci = i * 256 + tid;
            int row = ci >> 3, lc = ci & 7;
            int gc = lc ^ (row & 7);
            gload_lds16(A + (size_t)(row0 + row) * K + kt + gc * 8, As + ci * 8);
            gload_lds16(W + (size_t)(col0 + row) * K + kt + gc * 8, Bs + ci * 8);
        }
        __syncthreads();
        #pragma unroll
        for (int kc = 0; kc < 2; ++kc) {
            bf16x8 af[4], bfr[4];
            #pragma unroll
            for (int mi = 0; mi < 4; ++mi) {
                int r = wr * 64 + mi * 16 + lane15;
                af[mi] = *(const bf16x8*)(As + r * 64 + ((kc * 4 + quad) ^ (r & 7)) * 8);
            }
            #pragma unroll
            for (int ni = 0; ni < 4; ++ni) {
                int r = wc * 64 + ni * 16 + lane15;
                bfr[ni] = *(const bf16x8*)(Bs + r * 64 + ((kc * 4 + quad) ^ (r & 7)) * 8);
            }
            #pragma unroll
            for (int mi = 0; mi < 4; ++mi)
                #pragma unroll
                for (int ni = 0; ni < 4; ++ni)
                    acc[mi][ni] = __builtin_amdgcn_mfma_f32_16x16x32_bf16(
                        af[mi], bfr[ni], acc[mi][ni], 0, 0, 0);
        }
    }

    #pragma unroll
    for (int mi = 0; mi < 4; ++mi) {
        #pragma unroll
        for (int ni = 0; ni < 4; ++ni) {
            int col = col0 + wc * 64 + ni * 16 + lane15;
            float bv = bias[col];
            #pragma unroll
            for (int r = 0; r < 4; ++r) {
                int row = row0 + wr * 64 + mi * 16 + quad * 4 + r;
                float v = acc[mi][ni][r] + bv;
                if (BF16_OUT) ((short*)Cout)[(size_t)row * N + col] = f2bf(v);
                else          ((float*)Cout)[(size_t)row * N + col] = v;
            }
        }
    }
}

// ---------------------------------------------------------------------------
// RoPE + repack Q,K,V into MFMA-fragment-ordered buffers.
// qfrag/kfrag: [b][h][t16][kc4][lane64][8]  elem(row=t16*16+lane15, d=kc*32+quad*8+j)
// vfrag:       [b][h][kb64][dt8][kc2][lane64][8] elem(d=dt*16+lane15, key=kb*64+kc2*32+quad*8+j)
// Block per (64-row t-tile, h, b).
// ---------------------------------------------------------------------------
__global__ __launch_bounds__(256)
void rope_frag(const short* __restrict__ qkvb, short* __restrict__ qfrag,
               short* __restrict__ kfrag, short* __restrict__ vfrag)
{
    __shared__ short Vsm[64 * 132];
    const int tid = threadIdx.x;
    const int lane = tid & 63, w = tid >> 6;
    const int lane15 = lane & 15, quad = lane >> 4;
    const int t0 = blockIdx.x * 64, h = blockIdx.y, b = blockIdx.z;
    const int bh = b * NHEAD + h;

    // stage V tile [64 key][128 d] into LDS
    #pragma unroll
    for (int rep = 0; rep < 4; ++rep) {
        int ln = rep * 256 + tid;
        int vr = ln >> 4, c8 = (ln & 15) << 3;
        *(bf16x8*)&Vsm[vr * 132 + c8] =
            *(const bf16x8*)(qkvb + (size_t)(b * TSEQ + t0 + vr) * QROW + h * 384 + 256 + c8);
    }

    // rope q,k for row = t0 + w*16 + lane15
    const int row = t0 + w * 16 + lane15;
    const short* rp = qkvb + (size_t)(b * TSEQ + row) * QROW + h * 384;
    bf16x8 q[4], k[4];
    #pragma unroll
    for (int kc = 0; kc < 4; ++kc) {
        q[kc] = *(const bf16x8*)(rp + kc * 32 + quad * 8);
        k[kc] = *(const bf16x8*)(rp + 128 + kc * 32 + quad * 8);
    }
    const float sc = 0.022097086912079608f;   // 2048^-0.5 folded into q
    #pragma unroll
    for (int kc = 0; kc < 2; ++kc)
        #pragma unroll
        for (int j = 0; j < 8; ++j) {
            int d = kc * 32 + quad * 8 + j;       // 0..63
            float theta = exp2f(-(float)d * (13.287712379549449f / 64.0f));
            float sn, cs;
            sincosf((float)row * theta, &sn, &cs);
            float q1 = bf2f(q[kc][j]), q2 = bf2f(q[kc + 2][j]);
            float k1 = bf2f(k[kc][j]), k2 = bf2f(k[kc + 2][j]);
            q[kc][j]     = f2bf((q1 * cs - q2 * sn) * sc);
            q[kc + 2][j] = f2bf((q1 * sn + q2 * cs) * sc);
            k[kc][j]     = f2bf(k1 * cs - k2 * sn);
            k[kc + 2][j] = f2bf(k1 * sn + k2 * cs);
        }
    {
        size_t fb = (size_t)bh * 262144 + (size_t)(t0 / 16 + w) * 2048 + lane * 8;
        #pragma unroll
        for (int kc = 0; kc < 4; ++kc) {
            *(bf16x8*)(qfrag + fb + kc * 512) = q[kc];
            *(bf16x8*)(kfrag + fb + kc * 512) = k[kc];
        }
    }
    __syncthreads();
    // vfrag: wave w covers dt = 2w, 2w+1
    #pragma unroll
    for (int dd = 0; dd < 2; ++dd) {
        int dt = w * 2 + dd;
        int d = dt * 16 + lane15;
        #pragma unroll
        for (int kc2 = 0; kc2 < 2; ++kc2) {
            bf16x8 vv;
            #pragma unroll
            for (int j = 0; j < 8; ++j)
                vv[j] = Vsm[(kc2 * 32 + quad * 8 + j) * 132 + d];
            *(bf16x8*)(vfrag + (size_t)bh * 262144 + (size_t)(t0 >> 6) * 8192
                        + dt * 1024 + kc2 * 512 + lane * 8) = vv;
        }
    }
}

// ---------------------------------------------------------------------------
// Flash attention, S^T formulation. Block = 128-q tile (4 waves x 32q).
// K/V staged to LDS in fragment order (flat global_load_lds). Softmax per-lane
// (q on lane15), 2 cross-quad shuffles. P via per-wave LDS (no barrier).
// Uniform-cost pairing: qb = b ? 15-g : g, g=(x+h)&15 -> every CU pair = 34 tiles.
// ---------------------------------------------------------------------------
__global__ __launch_bounds__(256, 2)
void attn2(const short* __restrict__ qfrag, const short* __restrict__ kfrag,
           const short* __restrict__ vfrag, short* __restrict__ attnb)
{
    __shared__ char smem[51200];
    short* Ks = (short*)smem;                       // 16 KB
    short* Vs = (short*)(smem + 16384);             // 16 KB
    const int tid = threadIdx.x;
    const int lane = tid & 63, w = tid >> 6;
    const int lane15 = lane & 15, quad = lane >> 4;
    const int g = (blockIdx.x + blockIdx.y) & 15;
    const int qb = blockIdx.z ? (15 - g) : g;
    const int h = blockIdx.y, b = blockIdx.z;
    const int bh = b * NHEAD + h;
    const int q0 = qb * 128;
    short* Pscr = (short*)(smem + 32768 + w * 4608);  // [32 q][72 key] bf16

    // Q fragments
    bf16x8 qf[2][4];
    {
        const short* qp = qfrag + (size_t)bh * 262144
                        + (size_t)(qb * 8 + w * 2) * 2048 + lane * 8;
        #pragma unroll
        for (int nq = 0; nq < 2; ++nq)
            #pragma unroll
            for (int kc = 0; kc < 4; ++kc)
                qf[nq][kc] = *(const bf16x8*)(qp + nq * 2048 + kc * 512);
    }

    f32x4 acc[8][2];
    #pragma unroll
    for (int dt = 0; dt < 8; ++dt)
        #pragma unroll
        for (int nq = 0; nq < 2; ++nq)
            acc[dt][nq] = (f32x4){0.f, 0.f, 0.f, 0.f};
    float m_s[2] = {-3e38f, -3e38f}, l_s[2] = {0.f, 0.f};

    const short* kf_src = kfrag + (size_t)bh * 262144;
    const short* vf_src = vfrag + (size_t)bh * 262144;
    const int kb_max = (q0 + 127) >> 6;             // inclusive = 2qb+1
    const int diag0 = (q0 + w * 32) >> 6;           // mask from here on

    for (int kb = 0; kb <= kb_max; ++kb) {
        __syncthreads();
        #pragma unroll
        for (int i = 0; i < 4; ++i) {
            int ci = i * 256 + tid;
            gload_lds16(kf_src + (size_t)kb * 8192 + ci * 8, Ks + ci * 8);
            gload_lds16(vf_src + (size_t)kb * 8192 + ci * 8, Vs + ci * 8);
        }
        __syncthreads();

        // S^T = K Q^T : keys (4 mi tiles) x 32 q (2 nq)
        f32x4 st[2][4];
        #pragma unroll
        for (int nq = 0; nq < 2; ++nq)
            #pragma unroll
            for (int mi = 0; mi < 4; ++mi)
                st[nq][mi] = (f32x4){0.f, 0.f, 0.f, 0.f};
        #pragma unroll
        for (int mi = 0; mi < 4; ++mi) {
            bf16x8 kf4[4];
            #pragma unroll
            for (int kc = 0; kc < 4; ++kc)
                kf4[kc] = *(const bf16x8*)(Ks + ((mi * 4 + kc) * 64 + lane) * 8);
            #pragma unroll
            for (int kc = 0; kc < 4; ++kc)
                #pragma unroll
                for (int nq = 0; nq < 2; ++nq)
                    st[nq][mi] = __builtin_amdgcn_mfma_f32_16x16x32_bf16(
                        kf4[kc], qf[nq][kc], st[nq][mi], 0, 0, 0);
        }

        if (kb >= diag0) {      // causal mask (key on quad*4+r, q on lane15)
            #pragma unroll
            for (int nq = 0; nq < 2; ++nq) {
                int qg = q0 + w * 32 + nq * 16 + lane15;
                #pragma unroll
                for (int mi = 0; mi < 4; ++mi)
                    #pragma unroll
                    for (int r = 0; r < 4; ++r)
                        if (kb * 64 + mi * 16 + quad * 4 + r > qg)
                            st[nq][mi][r] = -3e38f;
            }
        }

        // online softmax per nq (state per-lane)
        #pragma unroll
        for (int nq = 0; nq < 2; ++nq) {
            float mt = st[nq][0][0];
            #pragma unroll
            for (int mi = 0; mi < 4; ++mi)
                #pragma unroll
                for (int r = 0; r < 4; ++r)
                    mt = fmaxf(mt, st[nq][mi][r]);
            mt = fmaxf(mt, __shfl_xor(mt, 16));
            mt = fmaxf(mt, __shfl_xor(mt, 32));
            float mn = fmaxf(m_s[nq], mt);
            float alpha = __expf(m_s[nq] - mn);
            m_s[nq] = mn;
            float sum = 0.f;
            #pragma unroll
            for (int mi = 0; mi < 4; ++mi)
                #pragma unroll
                for (int r = 0; r < 4; ++r) {
                    float p = __expf(st[nq][mi][r] - mn);
                    st[nq][mi][r] = p;
                    sum += p;
                }
            sum += __shfl_xor(sum, 16);
            sum += __shfl_xor(sum, 32);
            l_s[nq] = l_s[nq] * alpha + sum;
            #pragma unroll
            for (int dt = 0; dt < 8; ++dt) {
                acc[dt][nq][0] *= alpha; acc[dt][nq][1] *= alpha;
                acc[dt][nq][2] *= alpha; acc[dt][nq][3] *= alpha;
            }
            // P^T -> per-wave LDS [q][key], bf16, stride 72
            short* pr = Pscr + (nq * 16 + lane15) * 72 + quad * 4;
            #pragma unroll
            for (int mi = 0; mi < 4; ++mi) {
                unsigned lo = (unsigned)(unsigned short)f2bf(st[nq][mi][0])
                            | ((unsigned)(unsigned short)f2bf(st[nq][mi][1]) << 16);
                unsigned hi = (unsigned)(unsigned short)f2bf(st[nq][mi][2])
                            | ((unsigned)(unsigned short)f2bf(st[nq][mi][3]) << 16);
                *(unsigned*)(pr + mi * 16)     = lo;
                *(unsigned*)(pr + mi * 16 + 2) = hi;
            }
        }
        __asm__ volatile("s_waitcnt lgkmcnt(0)" ::: "memory");

        bf16x8 pb[2][2];
        #pragma unroll
        for (int nq = 0; nq < 2; ++nq)
            #pragma unroll
            for (int kc2 = 0; kc2 < 2; ++kc2)
                pb[nq][kc2] = *(const bf16x8*)
                    (Pscr + (nq * 16 + lane15) * 72 + kc2 * 32 + quad * 8);

        // O^T += V^T P^T
        #pragma unroll
        for (int dt = 0; dt < 8; ++dt)
            #pragma unroll
            for (int kc2 = 0; kc2 < 2; ++kc2) {
                bf16x8 vf = *(const bf16x8*)(Vs + ((dt * 2 + kc2) * 64 + lane) * 8);
                #pragma unroll
                for (int nq = 0; nq < 2; ++nq)
                    acc[dt][nq] = __builtin_amdgcn_mfma_f32_16x16x32_bf16(
                        vf, pb[nq][kc2], acc[dt][nq], 0, 0, 0);
            }
    }

    // epilogue: O^T/l -> LDS transpose [128 q][136 d] bf16 -> coalesced store
    __syncthreads();
    short* Eb = (short*)smem;
    #pragma unroll
    for (int nq = 0; nq < 2; ++nq) {
        float inv = 1.f / l_s[nq];
        int qrow = w * 32 + nq * 16 + lane15;
        #pragma unroll
        for (int dt = 0; dt < 8; ++dt) {
            unsigned lo = (unsigned)(unsigned short)f2bf(acc[dt][nq][0] * inv)
                        | ((unsigned)(unsigned short)f2bf(acc[dt][nq][1] * inv) << 16);
            unsigned hi = (unsigned)(unsigned short)f2bf(acc[dt][nq][2] * inv)
                        | ((unsigned)(unsigned short)f2bf(acc[dt][nq][3] * inv) << 16);
            *(unsigned*)(Eb + qrow * 136 + dt * 16 + quad * 4)     = lo;
            *(unsigned*)(Eb + qrow * 136 + dt * 16 + quad * 4 + 2) = hi;
        }
    }
    __syncthreads();
    {
        int r = tid >> 1, half = tid & 1;
        short* orow = attnb + (size_t)(b * TSEQ + q0 + r) * DM + h * 128 + half * 64;
        #pragma unroll
        for (int i = 0; i < 8; ++i)
            *(bf16x8*)(orow + i * 8) =
                *(const bf16x8*)(Eb + r * 136 + half * 64 + i * 8);
    }
}

// ---------------------------------------------------------------------------
extern "C" void kernel_launch(void* const* d_in, const int* in_sizes, int n_in,
                              void* d_out, int out_size, void* d_ws, size_t ws_size,
                              hipStream_t stream)
{
    const float* x     = (const float*)d_in[0];
    const float* w_qkv = (const float*)d_in[1];
    const float* b_qkv = (const float*)d_in[2];
    const float* w_out = (const float*)d_in[3];
    const float* b_out = (const float*)d_in[4];
    float* out = (float*)d_out;

    char* ws = (char*)d_ws;
    short* woutb = (short*)(ws);                   //  8.39 MB
    short* qkvb  = (short*)(ws + 8388608);         // 50.33 MB; attnb aliases
    short* qfrag = (short*)(ws + 58720256);        // 16.78 MB
    short* kfrag = (short*)(ws + 75497472);        // 16.78 MB
    short* vfrag = (short*)(ws + 92274688);        // 16.78 MB  (total 109.05 MB)
    short* xb    = (short*)(ws + 58720256);        // aliases qfrag (dead before rope)
    short* wqkvb = (short*)(ws + 75497472);        // aliases kfrag (dead before rope)
    short* attnb = qkvb;                           // qkvb dead after rope_frag

    cast_f32_bf16<<<4096, 256, 0, stream>>>(x, xb, 8388608);
    cast_f32_bf16<<<6144, 256, 0, stream>>>(w_qkv, wqkvb, 12582912);
    cast_f32_bf16<<<2048, 256, 0, stream>>>(w_out, woutb, 4194304);

    {   // qkv = x @ w_qkv^T + b_qkv  (bf16 out)
        dim3 g2(6144 / 128, 4096 / 128);
        gemm_bf16_nt<true><<<g2, 256, 0, stream>>>(xb, wqkvb, b_qkv, qkvb, 6144, 2048);
    }
    {   // rope + fragment repack
        dim3 g2(TSEQ / 64, NHEAD, BATCH);
        rope_frag<<<g2, 256, 0, stream>>>(qkvb, qfrag, kfrag, vfrag);
    }
    {   // flash attention
        dim3 g2(16, NHEAD, BATCH);
        attn2<<<g2, 256, 0, stream>>>(qfrag, kfrag, vfrag, attnb);
    }
    {   // out = attn @ w_out^T + b_out  (fp32 out)
        dim3 g2(2048 / 128, 4096 / 128);
        gemm_bf16_nt<false><<<g2, 256, 0, stream>>>(attnb, woutb, b_out, out, 2048, 2048);
    }
}

// Round 4
// 380.952 us; speedup vs baseline: 11.8644x; 1.0333x over previous
//
#include <hip/hip_runtime.h>
#include <math.h>

#define NHEAD 16
#define TSEQ  2048
#define BATCH 2
#define DM    2048

typedef __attribute__((ext_vector_type(8))) short bf16x8;
typedef __attribute__((ext_vector_type(4))) float f32x4;

__device__ __forceinline__ short f2bf(float f) {
    unsigned u = __builtin_bit_cast(unsigned, f);
    u += 0x7fff + ((u >> 16) & 1);          // RNE
    return (short)(u >> 16);
}
__device__ __forceinline__ float bf2f(short s) {
    unsigned u = ((unsigned)(unsigned short)s) << 16;
    return __builtin_bit_cast(float, u);
}
__device__ __forceinline__ void gload_lds16(const void* g, void* l) {
    __builtin_amdgcn_global_load_lds(
        (const __attribute__((address_space(1))) unsigned int*)g,
        (__attribute__((address_space(3))) unsigned int*)l, 16, 0, 0);
}

// ---------------------------------------------------------------------------
// merged fp32->bf16 casts: x (8.39M), w_qkv (12.58M), w_out (4.19M)
// ---------------------------------------------------------------------------
__global__ __launch_bounds__(256)
void cast_all(const float* __restrict__ x, short* __restrict__ xb,
              const float* __restrict__ wq, short* __restrict__ wqb,
              const float* __restrict__ wo, short* __restrict__ wob)
{
    int bid = blockIdx.x;
    const float* src; short* dst; int lb;
    if (bid < 4096)       { src = x;  dst = xb;  lb = bid; }
    else if (bid < 10240) { src = wq; dst = wqb; lb = bid - 4096; }
    else                  { src = wo; dst = wob; lb = bid - 10240; }
    int i = (lb * 256 + threadIdx.x) * 8;
    float4 a = *(const float4*)(src + i);
    float4 b = *(const float4*)(src + i + 4);
    bf16x8 o;
    o[0]=f2bf(a.x); o[1]=f2bf(a.y); o[2]=f2bf(a.z); o[3]=f2bf(a.w);
    o[4]=f2bf(b.x); o[5]=f2bf(b.y); o[6]=f2bf(b.z); o[7]=f2bf(b.w);
    *(bf16x8*)(dst + i) = o;
}

// ---------------------------------------------------------------------------
// QKV GEMM (m97 structure) with fused bias + RoPE + fragment repack epilogue.
// Each 128-col block is exactly one of {q,k,v} of one head (384 = 3*128).
// Epilogue: acc -> LDS tile [128 rows][136 d] bf16 -> rope (q/k) or
// transpose (v) -> fragment-ordered global buffers.
// qfrag/kfrag: [bh][t16][kc4][lane64][8]   (A-operand layout)
// vfrag:       [bh][kb64][dt8][kc2][lane64][8] (V^T A-operand layout)
// ---------------------------------------------------------------------------
__global__ __launch_bounds__(256)
void gemm_qkv_rope(const short* __restrict__ A, const short* __restrict__ W,
                   const float* __restrict__ bias, short* __restrict__ qfrag,
                   short* __restrict__ kfrag, short* __restrict__ vfrag)
{
    const int K = 2048;
    __shared__ short sm[17408];          // union: staging 16384 | tile 17408
    short* As = sm;                      // 128*64
    short* Bs = sm + 8192;
    const int tid = threadIdx.x;
    const int lane = tid & 63, w = tid >> 6;
    const int lane15 = lane & 15, quad = lane >> 4;
    const int wr = w >> 1, wc = w & 1;
    const int row0 = blockIdx.y * 128, col0 = blockIdx.x * 128;

    f32x4 acc[4][4];
    #pragma unroll
    for (int mi = 0; mi < 4; ++mi)
        #pragma unroll
        for (int ni = 0; ni < 4; ++ni)
            acc[mi][ni] = (f32x4){0.f, 0.f, 0.f, 0.f};

    for (int kt = 0; kt < K; kt += 64) {
        __syncthreads();
        #pragma unroll
        for (int i = 0; i < 4; ++i) {
            int ci = i * 256 + tid;
            int row = ci >> 3, lc = ci & 7;
            int gc = lc ^ (row & 7);
            gload_lds16(A + (size_t)(row0 + row) * K + kt + gc * 8, As + ci * 8);
            gload_lds16(W + (size_t)(col0 + row) * K + kt + gc * 8, Bs + ci * 8);
        }
        __syncthreads();
        #pragma unroll
        for (int kc = 0; kc < 2; ++kc) {
            bf16x8 af[4], bfr[4];
            #pragma unroll
            for (int mi = 0; mi < 4; ++mi) {
                int r = wr * 64 + mi * 16 + lane15;
                af[mi] = *(const bf16x8*)(As + r * 64 + ((kc * 4 + quad) ^ (r & 7)) * 8);
            }
            #pragma unroll
            for (int ni = 0; ni < 4; ++ni) {
                int r = wc * 64 + ni * 16 + lane15;
                bfr[ni] = *(const bf16x8*)(Bs + r * 64 + ((kc * 4 + quad) ^ (r & 7)) * 8);
            }
            #pragma unroll
            for (int mi = 0; mi < 4; ++mi)
                #pragma unroll
                for (int ni = 0; ni < 4; ++ni)
                    acc[mi][ni] = __builtin_amdgcn_mfma_f32_16x16x32_bf16(
                        af[mi], bfr[ni], acc[mi][ni], 0, 0, 0);
        }
    }

    // ---- epilogue ----
    const int head = col0 / 384;
    const int type = (col0 % 384) >> 7;      // 0=q 1=k 2=v
    const int b    = row0 >> 11;
    const int t0g  = row0 & 2047;
    const int bh   = b * NHEAD + head;

    __syncthreads();                          // all waves done reading As/Bs
    // acc (+bias) -> tile[row][d], stride 136
    #pragma unroll
    for (int ni = 0; ni < 4; ++ni) {
        int d = wc * 64 + ni * 16 + lane15;
        float bv = bias[col0 + d];
        #pragma unroll
        for (int mi = 0; mi < 4; ++mi) {
            int rowb = wr * 64 + mi * 16 + quad * 4;
            #pragma unroll
            for (int r = 0; r < 4; ++r)
                sm[(rowb + r) * 136 + d] = f2bf(acc[mi][ni][r] + bv);
        }
    }
    __syncthreads();

    if (type < 2) {   // q or k: rope + frag store
        const float sc = (type == 0) ? 0.022097086912079608f : 1.0f;
        short* dst = (type == 0 ? qfrag : kfrag) + (size_t)bh * 262144;
        #pragma unroll
        for (int it = 0; it < 4; ++it) {
            int c = it * 256 + tid;
            int l15 = c & 15, q_ = (c >> 4) & 3, kc = (c >> 6) & 1, rowhi = c >> 7;
            int lrow = rowhi * 16 + l15;
            int t = t0g + lrow;
            bf16x8 a8 = *(const bf16x8*)(sm + lrow * 136 + kc * 32 + q_ * 8);
            bf16x8 b8 = *(const bf16x8*)(sm + lrow * 136 + kc * 32 + q_ * 8 + 64);
            bf16x8 oa, ob;
            #pragma unroll
            for (int j = 0; j < 8; ++j) {
                int d = kc * 32 + q_ * 8 + j;
                // theta_rev = 10000^(-d/64) / (2*pi)
                float trev = exp2f(-(float)d * (13.287712379549449f / 64.0f))
                             * 0.15915494309189535f;
                float ang = (float)t * trev;
                float fr = ang - floorf(ang);
                float sn, cs;
                __sincosf(fr * 6.283185307179586f, &sn, &cs);
                float va = bf2f(a8[j]), vb = bf2f(b8[j]);
                oa[j] = f2bf((va * cs - vb * sn) * sc);
                ob[j] = f2bf((va * sn + vb * cs) * sc);
            }
            size_t base = (size_t)((t0g >> 4) + rowhi) * 2048 + (q_ * 16 + l15) * 8;
            *(bf16x8*)(dst + base + kc * 512)        = oa;
            *(bf16x8*)(dst + base + kc * 512 + 1024) = ob;
        }
    } else {          // v: transpose to vfrag
        short* dst = vfrag + (size_t)bh * 262144;
        #pragma unroll
        for (int it = 0; it < 8; ++it) {
            int c = it * 256 + tid;
            int lane_ = c & 63, rest = c >> 6;
            int q_ = lane_ >> 4, l15 = lane_ & 15;
            int dt = rest & 7, kc2 = (rest >> 3) & 1, kbt = rest >> 4;
            int d = dt * 16 + l15;
            bf16x8 v;
            #pragma unroll
            for (int j = 0; j < 8; ++j)
                v[j] = sm[(kbt * 64 + kc2 * 32 + q_ * 8 + j) * 136 + d];
            *(bf16x8*)(dst + (size_t)((t0g >> 6) + kbt) * 8192
                        + dt * 1024 + kc2 * 512 + lane_ * 8) = v;
        }
    }
}

// ---------------------------------------------------------------------------
// bf16 MFMA GEMM (NT) for out-projection (unchanged, fp32 out).
// ---------------------------------------------------------------------------
__global__ __launch_bounds__(256)
void gemm_out(const short* __restrict__ A, const short* __restrict__ W,
              const float* __restrict__ bias, float* __restrict__ Cout,
              int N, int K)
{
    __shared__ short As[128 * 64];
    __shared__ short Bs[128 * 64];
    const int tid = threadIdx.x;
    const int lane = tid & 63, w = tid >> 6;
    const int lane15 = lane & 15, quad = lane >> 4;
    const int wr = w >> 1, wc = w & 1;
    const int row0 = blockIdx.y * 128, col0 = blockIdx.x * 128;

    f32x4 acc[4][4];
    #pragma unroll
    for (int mi = 0; mi < 4; ++mi)
        #pragma unroll
        for (int ni = 0; ni < 4; ++ni)
            acc[mi][ni] = (f32x4){0.f, 0.f, 0.f, 0.f};

    for (int kt = 0; kt < K; kt += 64) {
        __syncthreads();
        #pragma unroll
        for (int i = 0; i < 4; ++i) {
            int ci = i * 256 + tid;
            int row = ci >> 3, lc = ci & 7;
            int gc = lc ^ (row & 7);
            gload_lds16(A + (size_t)(row0 + row) * K + kt + gc * 8, As + ci * 8);
            gload_lds16(W + (size_t)(col0 + row) * K + kt + gc * 8, Bs + ci * 8);
        }
        __syncthreads();
        #pragma unroll
        for (int kc = 0; kc < 2; ++kc) {
            bf16x8 af[4], bfr[4];
            #pragma unroll
            for (int mi = 0; mi < 4; ++mi) {
                int r = wr * 64 + mi * 16 + lane15;
                af[mi] = *(const bf16x8*)(As + r * 64 + ((kc * 4 + quad) ^ (r & 7)) * 8);
            }
            #pragma unroll
            for (int ni = 0; ni < 4; ++ni) {
                int r = wc * 64 + ni * 16 + lane15;
                bfr[ni] = *(const bf16x8*)(Bs + r * 64 + ((kc * 4 + quad) ^ (r & 7)) * 8);
            }
            #pragma unroll
            for (int mi = 0; mi < 4; ++mi)
                #pragma unroll
                for (int ni = 0; ni < 4; ++ni)
                    acc[mi][ni] = __builtin_amdgcn_mfma_f32_16x16x32_bf16(
                        af[mi], bfr[ni], acc[mi][ni], 0, 0, 0);
        }
    }

    #pragma unroll
    for (int mi = 0; mi < 4; ++mi)
        #pragma unroll
        for (int ni = 0; ni < 4; ++ni) {
            int col = col0 + wc * 64 + ni * 16 + lane15;
            float bv = bias[col];
            #pragma unroll
            for (int r = 0; r < 4; ++r) {
                int row = row0 + wr * 64 + mi * 16 + quad * 4 + r;
                Cout[(size_t)row * N + col] = acc[mi][ni][r] + bv;
            }
        }
}

// ---------------------------------------------------------------------------
// Flash attention (S^T form) with double-buffered K/V staging:
//   barrier -> issue DMA(kb+1 -> buf^1) -> compute(buf)  (real overlap).
// P-scratch halved (16 rows/wave, reused across the two nq halves).
// Fully-masked tiles skipped per wave. Uniform pairing balances CU load.
// ---------------------------------------------------------------------------
__global__ __launch_bounds__(256)
void attn3(const short* __restrict__ qfrag, const short* __restrict__ kfrag,
           const short* __restrict__ vfrag, short* __restrict__ attnb)
{
    __shared__ short KV[2][16384];        // per buf: K 8192 | V 8192 shorts
    __shared__ short Pb[4][1152];         // per wave: 16 q x stride 72
    const int tid = threadIdx.x;
    const int lane = tid & 63, w = tid >> 6;
    const int lane15 = lane & 15, quad = lane >> 4;
    const int g = (blockIdx.x + blockIdx.y) & 15;
    const int qb = blockIdx.z ? (15 - g) : g;
    const int h = blockIdx.y, b = blockIdx.z;
    const int bh = b * NHEAD + h;
    const int q0 = qb * 128;
    short* Pw = Pb[w];

    bf16x8 qf[2][4];
    {
        const short* qp = qfrag + (size_t)bh * 262144
                        + (size_t)(qb * 8 + w * 2) * 2048 + lane * 8;
        #pragma unroll
        for (int nq = 0; nq < 2; ++nq)
            #pragma unroll
            for (int kc = 0; kc < 4; ++kc)
                qf[nq][kc] = *(const bf16x8*)(qp + nq * 2048 + kc * 512);
    }

    f32x4 acc[8][2];
    #pragma unroll
    for (int dt = 0; dt < 8; ++dt)
        #pragma unroll
        for (int nq = 0; nq < 2; ++nq)
            acc[dt][nq] = (f32x4){0.f, 0.f, 0.f, 0.f};
    float m_s[2] = {-3e38f, -3e38f}, l_s[2] = {0.f, 0.f};

    const short* kf_src = kfrag + (size_t)bh * 262144;
    const short* vf_src = vfrag + (size_t)bh * 262144;
    const int kb_max = 2 * qb + 1;
    const int qtop = q0 + w * 32 + 31;           // wave's largest q index
    const int diag0 = (q0 + w * 32) >> 6;

    // prologue DMA for kb=0
    #pragma unroll
    for (int i = 0; i < 4; ++i) {
        int ci = i * 256 + tid;
        gload_lds16(kf_src + ci * 8, KV[0] + ci * 8);
        gload_lds16(vf_src + ci * 8, KV[0] + 8192 + ci * 8);
    }

    for (int kb = 0; kb <= kb_max; ++kb) {
        __syncthreads();                           // drains buf[kb&1] DMA
        if (kb < kb_max) {                         // prefetch next tile
            const short* ks = kf_src + (size_t)(kb + 1) * 8192;
            const short* vs = vf_src + (size_t)(kb + 1) * 8192;
            short* kd = KV[(kb + 1) & 1];
            #pragma unroll
            for (int i = 0; i < 4; ++i) {
                int ci = i * 256 + tid;
                gload_lds16(ks + ci * 8, kd + ci * 8);
                gload_lds16(vs + ci * 8, kd + 8192 + ci * 8);
            }
        }
        if (kb * 64 > qtop) continue;              // fully masked for this wave
        const short* Ks = KV[kb & 1];
        const short* Vs = Ks + 8192;

        // S^T = K Q^T
        f32x4 st[2][4];
        #pragma unroll
        for (int nq = 0; nq < 2; ++nq)
            #pragma unroll
            for (int mi = 0; mi < 4; ++mi)
                st[nq][mi] = (f32x4){0.f, 0.f, 0.f, 0.f};
        #pragma unroll
        for (int mi = 0; mi < 4; ++mi) {
            bf16x8 kf4[4];
            #pragma unroll
            for (int kc = 0; kc < 4; ++kc)
                kf4[kc] = *(const bf16x8*)(Ks + ((mi * 4 + kc) * 64 + lane) * 8);
            #pragma unroll
            for (int kc = 0; kc < 4; ++kc)
                #pragma unroll
                for (int nq = 0; nq < 2; ++nq)
                    st[nq][mi] = __builtin_amdgcn_mfma_f32_16x16x32_bf16(
                        kf4[kc], qf[nq][kc], st[nq][mi], 0, 0, 0);
        }

        if (kb >= diag0) {
            #pragma unroll
            for (int nq = 0; nq < 2; ++nq) {
                int qg = q0 + w * 32 + nq * 16 + lane15;
                #pragma unroll
                for (int mi = 0; mi < 4; ++mi)
                    #pragma unroll
                    for (int r = 0; r < 4; ++r)
                        if (kb * 64 + mi * 16 + quad * 4 + r > qg)
                            st[nq][mi][r] = -3e38f;
            }
        }

        // softmax + P->LDS (halved buffer, reused across nq)
        bf16x8 pb[2][2];
        #pragma unroll
        for (int nq = 0; nq < 2; ++nq) {
            float mt = st[nq][0][0];
            #pragma unroll
            for (int mi = 0; mi < 4; ++mi)
                #pragma unroll
                for (int r = 0; r < 4; ++r)
                    mt = fmaxf(mt, st[nq][mi][r]);
            mt = fmaxf(mt, __shfl_xor(mt, 16));
            mt = fmaxf(mt, __shfl_xor(mt, 32));
            float mn = fmaxf(m_s[nq], mt);
            float alpha = __expf(m_s[nq] - mn);
            m_s[nq] = mn;
            float sum = 0.f;
            #pragma unroll
            for (int mi = 0; mi < 4; ++mi)
                #pragma unroll
                for (int r = 0; r < 4; ++r) {
                    float p = __expf(st[nq][mi][r] - mn);
                    st[nq][mi][r] = p;
                    sum += p;
                }
            sum += __shfl_xor(sum, 16);
            sum += __shfl_xor(sum, 32);
            l_s[nq] = l_s[nq] * alpha + sum;
            #pragma unroll
            for (int dt = 0; dt < 8; ++dt) {
                acc[dt][nq][0] *= alpha; acc[dt][nq][1] *= alpha;
                acc[dt][nq][2] *= alpha; acc[dt][nq][3] *= alpha;
            }
            short* pr = Pw + lane15 * 72 + quad * 4;
            #pragma unroll
            for (int mi = 0; mi < 4; ++mi) {
                unsigned lo = (unsigned)(unsigned short)f2bf(st[nq][mi][0])
                            | ((unsigned)(unsigned short)f2bf(st[nq][mi][1]) << 16);
                unsigned hi = (unsigned)(unsigned short)f2bf(st[nq][mi][2])
                            | ((unsigned)(unsigned short)f2bf(st[nq][mi][3]) << 16);
                *(unsigned*)(pr + mi * 16)     = lo;
                *(unsigned*)(pr + mi * 16 + 2) = hi;
            }
            __asm__ volatile("s_waitcnt lgkmcnt(0)" ::: "memory");
            #pragma unroll
            for (int kc2 = 0; kc2 < 2; ++kc2)
                pb[nq][kc2] = *(const bf16x8*)(Pw + lane15 * 72 + kc2 * 32 + quad * 8);
            __asm__ volatile("s_waitcnt lgkmcnt(0)" ::: "memory");  // reads done before nq=1 overwrite
        }

        // O^T += V^T P^T  (each V fragment feeds both nq)
        #pragma unroll
        for (int dt = 0; dt < 8; ++dt)
            #pragma unroll
            for (int kc2 = 0; kc2 < 2; ++kc2) {
                bf16x8 vf = *(const bf16x8*)(Vs + ((dt * 2 + kc2) * 64 + lane) * 8);
                #pragma unroll
                for (int nq = 0; nq < 2; ++nq)
                    acc[dt][nq] = __builtin_amdgcn_mfma_f32_16x16x32_bf16(
                        vf, pb[nq][kc2], acc[dt][nq], 0, 0, 0);
            }
    }

    // epilogue: O^T/l -> LDS transpose -> coalesced bf16 store
    __syncthreads();
    short* Eb = KV[0];                    // 128 x 136
    #pragma unroll
    for (int nq = 0; nq < 2; ++nq) {
        float inv = 1.f / l_s[nq];
        int qrow = w * 32 + nq * 16 + lane15;
        #pragma unroll
        for (int dt = 0; dt < 8; ++dt) {
            unsigned lo = (unsigned)(unsigned short)f2bf(acc[dt][nq][0] * inv)
                        | ((unsigned)(unsigned short)f2bf(acc[dt][nq][1] * inv) << 16);
            unsigned hi = (unsigned)(unsigned short)f2bf(acc[dt][nq][2] * inv)
                        | ((unsigned)(unsigned short)f2bf(acc[dt][nq][3] * inv) << 16);
            *(unsigned*)(Eb + qrow * 136 + dt * 16 + quad * 4)     = lo;
            *(unsigned*)(Eb + qrow * 136 + dt * 16 + quad * 4 + 2) = hi;
        }
    }
    __syncthreads();
    {
        int r = tid >> 1, half = tid & 1;
        short* orow = attnb + (size_t)(b * TSEQ + q0 + r) * DM + h * 128 + half * 64;
        #pragma unroll
        for (int i = 0; i < 8; ++i)
            *(bf16x8*)(orow + i * 8) =
                *(const bf16x8*)(Eb + r * 136 + half * 64 + i * 8);
    }
}

// ---------------------------------------------------------------------------
extern "C" void kernel_launch(void* const* d_in, const int* in_sizes, int n_in,
                              void* d_out, int out_size, void* d_ws, size_t ws_size,
                              hipStream_t stream)
{
    const float* x     = (const float*)d_in[0];
    const float* w_qkv = (const float*)d_in[1];
    const float* b_qkv = (const float*)d_in[2];
    const float* w_out = (const float*)d_in[3];
    const float* b_out = (const float*)d_in[4];
    float* out = (float*)d_out;

    char* ws = (char*)d_ws;
    short* xb    = (short*)(ws);                 // 16.78 MB (reused as attnb)
    short* wqkvb = (short*)(ws + 16777216);      // 25.17 MB
    short* woutb = (short*)(ws + 41943040);      //  8.39 MB
    short* qfrag = (short*)(ws + 50331648);      // 16.78 MB
    short* kfrag = (short*)(ws + 67108864);      // 16.78 MB
    short* vfrag = (short*)(ws + 83886080);      // 16.78 MB  (total 100.66 MB)
    short* attnb = xb;                           // x dead after QKV GEMM

    cast_all<<<12288, 256, 0, stream>>>(x, xb, w_qkv, wqkvb, w_out, woutb);

    {   // qkv GEMM + bias + rope + fragment repack
        dim3 g2(48, 32);
        gemm_qkv_rope<<<g2, 256, 0, stream>>>(xb, wqkvb, b_qkv, qfrag, kfrag, vfrag);
    }
    {   // flash attention
        dim3 g2(16, NHEAD, BATCH);
        attn3<<<g2, 256, 0, stream>>>(qfrag, kfrag, vfrag, attnb);
    }
    {   // out = attn @ w_out^T + b_out
        dim3 g2(16, 32);
        gemm_out<<<g2, 256, 0, stream>>>(attnb, woutb, b_out, out, 2048, 2048);
    }
}